// Round 2
// baseline (861.743 us; speedup 1.0000x reference)
//
#include <hip/hip_runtime.h>

#define NODE 128
#define EDGE 64
#define OUTC 128
#define KTOT 320          // NODE + NODE + EDGE  (self | atom-sum | bond-sum)
#define NPD 125000
#define N_ATOMS_C 500000
#define BROWS 32          // rows per batch (2 MFMA m-tiles)
#define NBATCH 8          // 4 batches of seg P + 4 of seg Q per block
#define ROWS_PER_PHASE 128
#define NCHUNK 977        // ceil(125000 / 128)
#define LDST 328          // padded LDS row stride (bf16 units)
#define BN_EPS 1e-5f

typedef short bf16x8 __attribute__((ext_vector_type(8)));
typedef float floatx4 __attribute__((ext_vector_type(4)));

__device__ __forceinline__ unsigned short f2bf(float f) {
    unsigned u = __float_as_uint(f);
    u += 0x7fffu + ((u >> 16) & 1u);     // round-to-nearest-even
    return (unsigned short)(u >> 16);
}
__device__ __forceinline__ unsigned pack2(float a, float b) {
    return (unsigned)f2bf(a) | ((unsigned)f2bf(b) << 16);
}
__device__ __forceinline__ void add4(float4& a, const float4 b) {
    a.x += b.x; a.y += b.y; a.z += b.z; a.w += b.w;
}

// ws layout: [0..255] f32 stats (sum | sumsq -> mean | rstd), then bf16 Wcat[4][128][320]
__global__ __launch_bounds__(256) void pack_weights_kernel(
    const float* __restrict__ w1, const float* __restrict__ w2,
    const float* __restrict__ w3, const float* __restrict__ w4,
    const float* __restrict__ W_self, float* __restrict__ stats,
    unsigned short* __restrict__ Wcat)
{
    if (blockIdx.x == 0 && threadIdx.x < 256) stats[threadIdx.x] = 0.f;
    const int idx = blockIdx.x * 256 + threadIdx.x;      // 4*128*320 = 163840
    if (idx >= 4 * OUTC * KTOT) return;
    const int d   = idx / (OUTC * KTOT);
    const int rem = idx % (OUTC * KTOT);
    const int n = rem / KTOT, k = rem % KTOT;
    const float* wd = (d == 0) ? w1 : (d == 1) ? w2 : (d == 2) ? w3 : w4;
    const float v = (k < NODE) ? W_self[n * NODE + k]
                               : wd[n * (NODE + EDGE) + (k - NODE)];
    Wcat[idx] = f2bf(v);
}

// One block processes 4 batches of segment SP then 4 of SQ (deg SP+1 + deg SQ+1 == 5
// -> every block has identical gather cost; no degree tail).
// 3-stage pipeline: idx(t+2) -> feat(t+1) -> pack/compute(t). Index-load latency
// hides under a full batch; feature loads fly across the raw barrier (no vmcnt drain).
template<int SP, int SQ>
__device__ __forceinline__ void run_pair(
    const float4* __restrict__ ar, const float4* __restrict__ br,
    const int* __restrict__ aP, const int* __restrict__ bP,
    const int* __restrict__ aQ, const int* __restrict__ bQ,
    const unsigned short* __restrict__ Wcat, const float* __restrict__ bias,
    float* __restrict__ out, float* __restrict__ stats,
    unsigned short (*s_feat)[BROWS][LDST], float* s_sum, float* s_sq,
    const int chunk, const int tid)
{
    constexpr int DP = SP + 1, DQ = SQ + 1;
    const int w    = tid >> 6;
    const int lane = tid & 63;
    const int quad = lane >> 4;
    const int lrow = lane & 15;
    const int gr   = tid >> 3;     // gather: 8 threads per row, 32 rows
    const int gt   = tid & 7;

    // ---- B slab in registers: 2 n-tiles x 10 k-steps = 80 VGPRs ----
    bf16x8 breg[2][10];
    {
        const unsigned short* Wc = Wcat + SP * OUTC * KTOT;
        #pragma unroll
        for (int nt = 0; nt < 2; ++nt) {
            const int n = w * 32 + nt * 16 + lrow;
            #pragma unroll
            for (int ks = 0; ks < 10; ++ks)
                breg[nt][ks] = *reinterpret_cast<const bf16x8*>(Wc + n * KTOT + quad * 8 + ks * 32);
        }
    }
    float bias_v[2];
    bias_v[0] = bias[w * 32 + lrow];
    bias_v[1] = bias[w * 32 + 16 + lrow];
    float lsum[2] = {0.f, 0.f}, lsq[2] = {0.f, 0.f};

    // ---- staging registers ----
    float4 st_s[4];     // self  [h*2 + half]
    float4 st_a[16];    // atoms [j*4 + h*2 + half]
    float4 st_b[8];     // bonds [j*2 + half]
    int ia[2][4], ib[2][4];   // ping-pong index buffers (t & 1)

    auto issue_idx = [&](int t) {            // t folds to constant under unroll
        const int dg = (t < 4) ? DP : DQ;
        const int* ax = (t < 4) ? aP : aQ;
        const int* bx = (t < 4) ? bP : bQ;
        const int r0 = chunk * ROWS_PER_PHASE + (t & 3) * BROWS + gr;
        const int rc = (r0 < NPD) ? r0 : (NPD - 1);
        int* ia_ = ia[t & 1]; int* ib_ = ib[t & 1];
        #pragma unroll
        for (int j = 0; j < 4; ++j)
            if (j < dg) { ia_[j] = ax[rc * dg + j]; ib_[j] = bx[rc * dg + j]; }
    };

    auto issue_feat = [&](int t) {
        const int dg = (t < 4) ? DP : DQ;
        const int sg = (t < 4) ? SP : SQ;
        const int r0 = chunk * ROWS_PER_PHASE + (t & 3) * BROWS + gr;
        const int rc = (r0 < NPD) ? r0 : (NPD - 1);
        const size_t gi = (size_t)(sg * NPD) + rc;
        const int* ia_ = ia[t & 1]; const int* ib_ = ib[t & 1];
        #pragma unroll
        for (int h = 0; h < 2; ++h) {
            const int c = h * 16 + gt * 2;           // float4 idx within 128-f row
            st_s[h * 2 + 0] = ar[gi * 32 + c];
            st_s[h * 2 + 1] = ar[gi * 32 + c + 1];
            #pragma unroll
            for (int j = 0; j < 4; ++j)
                if (j < dg) {
                    st_a[j * 4 + h * 2 + 0] = ar[(size_t)ia_[j] * 32 + c];
                    st_a[j * 4 + h * 2 + 1] = ar[(size_t)ia_[j] * 32 + c + 1];
                }
        }
        const int cb = gt * 2;                       // float4 idx within 64-f row
        #pragma unroll
        for (int j = 0; j < 4; ++j)
            if (j < dg) {
                st_b[j * 2 + 0] = br[(size_t)ib_[j] * 16 + cb];
                st_b[j * 2 + 1] = br[(size_t)ib_[j] * 16 + cb + 1];
            }
    };

    auto pack_lds = [&](int t) {
        const int dg = (t < 4) ? DP : DQ;
        unsigned short (*sf)[LDST] = s_feat[t & 1];
        #pragma unroll
        for (int h = 0; h < 2; ++h) {
            const int k0 = h * 64 + gt * 8;
            uint4 p;
            p.x = pack2(st_s[h * 2].x, st_s[h * 2].y);
            p.y = pack2(st_s[h * 2].z, st_s[h * 2].w);
            p.z = pack2(st_s[h * 2 + 1].x, st_s[h * 2 + 1].y);
            p.w = pack2(st_s[h * 2 + 1].z, st_s[h * 2 + 1].w);
            *reinterpret_cast<uint4*>(&sf[gr][k0]) = p;
            float4 u0 = st_a[h * 2], u1 = st_a[h * 2 + 1];
            #pragma unroll
            for (int j = 1; j < 4; ++j)
                if (j < dg) { add4(u0, st_a[j * 4 + h * 2]); add4(u1, st_a[j * 4 + h * 2 + 1]); }
            p.x = pack2(u0.x, u0.y); p.y = pack2(u0.z, u0.w);
            p.z = pack2(u1.x, u1.y); p.w = pack2(u1.z, u1.w);
            *reinterpret_cast<uint4*>(&sf[gr][NODE + k0]) = p;
        }
        {
            const int k0 = gt * 8;
            float4 u0 = st_b[0], u1 = st_b[1];
            #pragma unroll
            for (int j = 1; j < 4; ++j)
                if (j < dg) { add4(u0, st_b[j * 2]); add4(u1, st_b[j * 2 + 1]); }
            uint4 p;
            p.x = pack2(u0.x, u0.y); p.y = pack2(u0.z, u0.w);
            p.z = pack2(u1.x, u1.y); p.w = pack2(u1.z, u1.w);
            *reinterpret_cast<uint4*>(&sf[gr][2 * NODE + k0]) = p;
        }
    };

    auto compute_store = [&](int t) {
        const int sg = (t < 4) ? SP : SQ;
        const int base = chunk * ROWS_PER_PHASE + (t & 3) * BROWS;
        unsigned short (*sfr)[LDST] = s_feat[t & 1];
        floatx4 acc[2][2];
        #pragma unroll
        for (int mt = 0; mt < 2; ++mt)
            #pragma unroll
            for (int nt = 0; nt < 2; ++nt) {
                acc[mt][nt][0] = bias_v[nt]; acc[mt][nt][1] = bias_v[nt];
                acc[mt][nt][2] = bias_v[nt]; acc[mt][nt][3] = bias_v[nt];
            }
        #pragma unroll
        for (int ks = 0; ks < 10; ++ks) {
            bf16x8 af0 = *reinterpret_cast<const bf16x8*>(&sfr[lrow][quad * 8 + ks * 32]);
            bf16x8 af1 = *reinterpret_cast<const bf16x8*>(&sfr[16 + lrow][quad * 8 + ks * 32]);
            acc[0][0] = __builtin_amdgcn_mfma_f32_16x16x32_bf16(af0, breg[0][ks], acc[0][0], 0, 0, 0);
            acc[0][1] = __builtin_amdgcn_mfma_f32_16x16x32_bf16(af0, breg[1][ks], acc[0][1], 0, 0, 0);
            acc[1][0] = __builtin_amdgcn_mfma_f32_16x16x32_bf16(af1, breg[0][ks], acc[1][0], 0, 0, 0);
            acc[1][1] = __builtin_amdgcn_mfma_f32_16x16x32_bf16(af1, breg[1][ks], acc[1][1], 0, 0, 0);
        }
        #pragma unroll
        for (int mt = 0; mt < 2; ++mt) {
            #pragma unroll
            for (int nt = 0; nt < 2; ++nt) {
                const int n = w * 32 + nt * 16 + lrow;
                #pragma unroll
                for (int r = 0; r < 4; ++r) {
                    const int m = mt * 16 + quad * 4 + r;
                    const int row = base + m;
                    if (row < NPD) {
                        const float v = acc[mt][nt][r];
                        out[(size_t)(sg * NPD + row) * OUTC + n] = v;
                        lsum[nt] += v; lsq[nt] += v * v;
                    }
                }
            }
        }
    };

    // ---- 3-stage pipelined batch loop ----
    issue_idx(0);
    issue_feat(0);            // one exposed idx wait per block (prologue only)
    issue_idx(1);

    #pragma unroll
    for (int bb = 0; bb < NBATCH; ++bb) {
        const bool v0 = (chunk * ROWS_PER_PHASE + (bb & 3) * BROWS) < NPD;
        if (v0) pack_lds(bb);
        // keep st_* live-range single: next feat loads must not hoist above pack
        __builtin_amdgcn_sched_barrier(0);
        if (bb + 1 < NBATCH && (chunk * ROWS_PER_PHASE + ((bb + 1) & 3) * BROWS) < NPD)
            issue_feat(bb + 1);
        if (bb + 2 < NBATCH && (chunk * ROWS_PER_PHASE + ((bb + 2) & 3) * BROWS) < NPD)
            issue_idx(bb + 2);
        if (v0) {
            asm volatile("s_waitcnt lgkmcnt(0)" ::: "memory");  // ds_writes visible
            __builtin_amdgcn_s_barrier();                        // NO vmcnt drain
            compute_store(bb);
        }
        if (bb == 3) {   // switch B slab to segment SQ (Wcat is L2-resident)
            const unsigned short* Wc = Wcat + SQ * OUTC * KTOT;
            #pragma unroll
            for (int nt = 0; nt < 2; ++nt) {
                const int n = w * 32 + nt * 16 + lrow;
                #pragma unroll
                for (int ks = 0; ks < 10; ++ks)
                    breg[nt][ks] = *reinterpret_cast<const bf16x8*>(Wc + n * KTOT + quad * 8 + ks * 32);
            }
        }
    }

    atomicAdd(&s_sum[w * 32 + lrow], lsum[0]);
    atomicAdd(&s_sq [w * 32 + lrow], lsq[0]);
    atomicAdd(&s_sum[w * 32 + 16 + lrow], lsum[1]);
    atomicAdd(&s_sq [w * 32 + 16 + lrow], lsq[1]);
    __syncthreads();
    if (tid < OUTC) {
        atomicAdd(&stats[tid], s_sum[tid]);
        atomicAdd(&stats[OUTC + tid], s_sq[tid]);
    }
}

__global__ __launch_bounds__(256, 2) void compute_x_kernel(
    const float* __restrict__ atom_repr, const float* __restrict__ bond_repr,
    const int* __restrict__ a1, const int* __restrict__ b1,
    const int* __restrict__ a2, const int* __restrict__ b2,
    const int* __restrict__ a3, const int* __restrict__ b3,
    const int* __restrict__ a4, const int* __restrict__ b4,
    const unsigned short* __restrict__ Wcat, const float* __restrict__ bias,
    float* __restrict__ out, float* __restrict__ stats)
{
    __shared__ unsigned short s_feat[2][BROWS][LDST];   // ~42 KB -> 3 blocks/CU
    __shared__ float s_sum[OUTC], s_sq[OUTC];

    const int tid = threadIdx.x;
    if (tid < OUTC) { s_sum[tid] = 0.f; s_sq[tid] = 0.f; }

    const int pair  = blockIdx.x & 1;       // interleave pairs across CUs
    const int chunk = blockIdx.x >> 1;
    const float4* ar = (const float4*)atom_repr;
    const float4* br = (const float4*)bond_repr;

    if (pair == 0)
        run_pair<0, 3>(ar, br, a1, b1, a4, b4, Wcat, bias, out, stats,
                       s_feat, s_sum, s_sq, chunk, tid);
    else
        run_pair<1, 2>(ar, br, a2, b2, a3, b3, Wcat, bias, out, stats,
                       s_feat, s_sum, s_sq, chunk, tid);
}

__global__ void finalize_stats_kernel(float* stats) {
    const int o = threadIdx.x;  // 128
    const float inv_n = 1.0f / (float)N_ATOMS_C;
    const float mean = stats[o] * inv_n;
    const float var  = stats[OUTC + o] * inv_n - mean * mean;
    stats[o] = mean;
    stats[OUTC + o] = rsqrtf(var + BN_EPS);
}

#define BN_TOT (N_ATOMS_C * (OUTC / 4))   // 16,000,000 float4
#define BN_BLOCKS 2048

__global__ __launch_bounds__(256) void bn_relu_kernel(float* __restrict__ x,
                                                      const float* __restrict__ stats) {
    const int gid = blockIdx.x * 256 + threadIdx.x;
    // stride is a multiple of 32 -> channel quad (e & 31) is loop-invariant
    const int c4 = gid & 31;
    const float4 m = ((const float4*)stats)[c4];
    const float4 s = ((const float4*)stats)[32 + c4];
    const int stride = BN_BLOCKS * 256;
    for (size_t e = (size_t)gid; e < (size_t)BN_TOT; e += stride) {
        float4 v = ((float4*)x)[e];
        v.x = fmaxf((v.x - m.x) * s.x, 0.f);
        v.y = fmaxf((v.y - m.y) * s.y, 0.f);
        v.z = fmaxf((v.z - m.z) * s.z, 0.f);
        v.w = fmaxf((v.w - m.w) * s.w, 0.f);
        ((float4*)x)[e] = v;
    }
}

extern "C" void kernel_launch(void* const* d_in, const int* in_sizes, int n_in,
                              void* d_out, int out_size, void* d_ws, size_t ws_size,
                              hipStream_t stream) {
    const float* atom_repr = (const float*)d_in[0];
    const float* bond_repr = (const float*)d_in[1];
    const int*   a1 = (const int*)d_in[2];
    const int*   b1 = (const int*)d_in[3];
    const float* w1 = (const float*)d_in[4];
    const int*   a2 = (const int*)d_in[5];
    const int*   b2 = (const int*)d_in[6];
    const float* w2 = (const float*)d_in[7];
    const int*   a3 = (const int*)d_in[8];
    const int*   b3 = (const int*)d_in[9];
    const float* w3 = (const float*)d_in[10];
    const int*   a4 = (const int*)d_in[11];
    const int*   b4 = (const int*)d_in[12];
    const float* w4 = (const float*)d_in[13];
    const float* W_self = (const float*)d_in[14];
    const float* bias   = (const float*)d_in[15];

    float* out   = (float*)d_out;
    float* stats = (float*)d_ws;                                    // 256 f32
    unsigned short* Wcat = (unsigned short*)((char*)d_ws + 1024);   // bf16[4][128][320]

    pack_weights_kernel<<<(4 * OUTC * KTOT + 255) / 256, 256, 0, stream>>>(
        w1, w2, w3, w4, W_self, stats, Wcat);

    compute_x_kernel<<<NCHUNK * 2, 256, 0, stream>>>(
        atom_repr, bond_repr, a1, b1, a2, b2, a3, b3, a4, b4,
        Wcat, bias, out, stats);

    finalize_stats_kernel<<<1, 128, 0, stream>>>(stats);

    bn_relu_kernel<<<BN_BLOCKS, 256, 0, stream>>>(out, stats);
}

// Round 3
// 808.781 us; speedup vs baseline: 1.0655x; 1.0655x over previous
//
#include <hip/hip_runtime.h>

#define NODE 128
#define EDGE 64
#define OUTC 128
#define KTOT 320          // NODE + NODE + EDGE  (self | atom-sum | bond-sum)
#define NPD 125000
#define N_ATOMS_C 500000
#define BROWS 32          // rows per batch (2 MFMA m-tiles)
#define NB 4              // batches per block
#define NBLK 977          // ceil(125000 / 128)
#define LDST 328          // padded LDS row stride (bf16 units): 656 B -> 2-way-free banks
#define BN_EPS 1e-5f

typedef short bf16x8 __attribute__((ext_vector_type(8)));
typedef float floatx4 __attribute__((ext_vector_type(4)));

__device__ __forceinline__ unsigned short f2bf(float f) {
    unsigned u = __float_as_uint(f);
    u += 0x7fffu + ((u >> 16) & 1u);     // round-to-nearest-even
    return (unsigned short)(u >> 16);
}
__device__ __forceinline__ unsigned pack2(float a, float b) {
    return (unsigned)f2bf(a) | ((unsigned)f2bf(b) << 16);
}
__device__ __forceinline__ void add4(float4& a, const float4 b) {
    a.x += b.x; a.y += b.y; a.z += b.z; a.w += b.w;
}

// ws layout: [0..255] f32 stats (sum | sumsq -> mean | rstd), then bf16 Wcat[4][128][320]
__global__ __launch_bounds__(256) void pack_weights_kernel(
    const float* __restrict__ w1, const float* __restrict__ w2,
    const float* __restrict__ w3, const float* __restrict__ w4,
    const float* __restrict__ W_self, float* __restrict__ stats,
    unsigned short* __restrict__ Wcat)
{
    if (blockIdx.x == 0 && threadIdx.x < 256) stats[threadIdx.x] = 0.f;
    const int idx = blockIdx.x * 256 + threadIdx.x;      // 4*128*320 = 163840
    if (idx >= 4 * OUTC * KTOT) return;
    const int d   = idx / (OUTC * KTOT);
    const int rem = idx % (OUTC * KTOT);
    const int n = rem / KTOT, k = rem % KTOT;
    const float* wd = (d == 0) ? w1 : (d == 1) ? w2 : (d == 2) ? w3 : w4;
    const float v = (k < NODE) ? W_self[n * NODE + k]
                               : wd[n * (NODE + EDGE) + (k - NODE)];
    Wcat[idx] = f2bf(v);
}

// One block = NB batches of 32 rows of ONE segment; degree is a template constant.
// 3-stage pipeline: idx(t+2) -> feat(t+1) -> pack/compute(t).
// Index registers: two NAMED sets (A/B) selected at compile time at each call site
// (idx values die when the feat loads are issued, so two sets suffice) -> no
// runtime-indexed register arrays -> no scratch (R2's regression).
template<int DEG>
__device__ __forceinline__ void run_seg(
    const float4* __restrict__ ar, const float4* __restrict__ br,
    const int* __restrict__ aidx, const int* __restrict__ bidx,
    const unsigned short* __restrict__ Wcat, const float* __restrict__ bias,
    float* __restrict__ out, float* __restrict__ stats,
    unsigned short (*s_feat)[BROWS][LDST], float* s_sum, float* s_sq,
    const int chunk, const int tid)
{
    constexpr int SEG = DEG - 1;
    const int w    = tid >> 6;
    const int lane = tid & 63;
    const int quad = lane >> 4;
    const int lrow = lane & 15;
    const int gr   = tid >> 3;     // gather: 8 threads per row, 32 rows
    const int gt   = tid & 7;

    // ---- B slab in registers: 2 n-tiles x 10 k-steps = 80 regs ----
    bf16x8 breg[2][10];
    {
        const unsigned short* Wc = Wcat + SEG * OUTC * KTOT;
        #pragma unroll
        for (int nt = 0; nt < 2; ++nt) {
            const int n = w * 32 + nt * 16 + lrow;
            #pragma unroll
            for (int ks = 0; ks < 10; ++ks)
                breg[nt][ks] = *reinterpret_cast<const bf16x8*>(Wc + n * KTOT + quad * 8 + ks * 32);
        }
    }
    float bias_v[2];
    bias_v[0] = bias[w * 32 + lrow];
    bias_v[1] = bias[w * 32 + 16 + lrow];
    float lsum[2] = {0.f, 0.f}, lsq[2] = {0.f, 0.f};

    // ---- staging registers (single feat set; consumed by pack before re-issue) ----
    float4 st_s[4];          // self  [h*2 + half]
    float4 st_a[DEG][4];     // atoms [j][h*2 + half]
    float4 st_b[DEG][2];     // bonds [j][half]
    int iaA[DEG], ibA[DEG];  // named index sets -- compile-time selected
    int iaB[DEG], ibB[DEG];

    const int rbase = chunk * (BROWS * NB);

    auto issue_idx = [&](int t, int* ia_, int* ib_) {
        const int r0 = rbase + t * BROWS + gr;
        const int rc = (r0 < NPD) ? r0 : (NPD - 1);
        #pragma unroll
        for (int j = 0; j < DEG; ++j) {
            ia_[j] = aidx[rc * DEG + j];
            ib_[j] = bidx[rc * DEG + j];
        }
    };
    auto issue_feat = [&](int t, const int* ia_, const int* ib_) {
        const int r0 = rbase + t * BROWS + gr;
        const int rc = (r0 < NPD) ? r0 : (NPD - 1);
        const size_t gi = (size_t)(SEG * NPD) + rc;
        #pragma unroll
        for (int h = 0; h < 2; ++h) {
            const int c = h * 16 + gt * 2;           // float4 idx within 128-f row
            st_s[h * 2 + 0] = ar[gi * 32 + c];
            st_s[h * 2 + 1] = ar[gi * 32 + c + 1];
            #pragma unroll
            for (int j = 0; j < DEG; ++j) {
                st_a[j][h * 2 + 0] = ar[(size_t)ia_[j] * 32 + c];
                st_a[j][h * 2 + 1] = ar[(size_t)ia_[j] * 32 + c + 1];
            }
        }
        const int cb = gt * 2;                       // float4 idx within 64-f row
        #pragma unroll
        for (int j = 0; j < DEG; ++j) {
            st_b[j][0] = br[(size_t)ib_[j] * 16 + cb];
            st_b[j][1] = br[(size_t)ib_[j] * 16 + cb + 1];
        }
    };
    auto pack_lds = [&](unsigned short (*sf)[LDST]) {
        #pragma unroll
        for (int h = 0; h < 2; ++h) {
            const int k0 = h * 64 + gt * 8;
            uint4 p;
            p.x = pack2(st_s[h * 2].x, st_s[h * 2].y);
            p.y = pack2(st_s[h * 2].z, st_s[h * 2].w);
            p.z = pack2(st_s[h * 2 + 1].x, st_s[h * 2 + 1].y);
            p.w = pack2(st_s[h * 2 + 1].z, st_s[h * 2 + 1].w);
            *reinterpret_cast<uint4*>(&sf[gr][k0]) = p;
            float4 u0 = st_a[0][h * 2], u1 = st_a[0][h * 2 + 1];
            #pragma unroll
            for (int j = 1; j < DEG; ++j) { add4(u0, st_a[j][h * 2]); add4(u1, st_a[j][h * 2 + 1]); }
            p.x = pack2(u0.x, u0.y); p.y = pack2(u0.z, u0.w);
            p.z = pack2(u1.x, u1.y); p.w = pack2(u1.z, u1.w);
            *reinterpret_cast<uint4*>(&sf[gr][NODE + k0]) = p;
        }
        {
            const int k0 = gt * 8;
            float4 u0 = st_b[0][0], u1 = st_b[0][1];
            #pragma unroll
            for (int j = 1; j < DEG; ++j) { add4(u0, st_b[j][0]); add4(u1, st_b[j][1]); }
            uint4 p;
            p.x = pack2(u0.x, u0.y); p.y = pack2(u0.z, u0.w);
            p.z = pack2(u1.x, u1.y); p.w = pack2(u1.z, u1.w);
            *reinterpret_cast<uint4*>(&sf[gr][2 * NODE + k0]) = p;
        }
    };
    auto compute_store = [&](int t, unsigned short (*sfr)[LDST]) {
        const int base = rbase + t * BROWS;
        floatx4 acc[2][2];
        #pragma unroll
        for (int mt = 0; mt < 2; ++mt)
            #pragma unroll
            for (int nt = 0; nt < 2; ++nt) {
                acc[mt][nt][0] = bias_v[nt]; acc[mt][nt][1] = bias_v[nt];
                acc[mt][nt][2] = bias_v[nt]; acc[mt][nt][3] = bias_v[nt];
            }
        #pragma unroll
        for (int ks = 0; ks < 10; ++ks) {
            bf16x8 af0 = *reinterpret_cast<const bf16x8*>(&sfr[lrow][quad * 8 + ks * 32]);
            bf16x8 af1 = *reinterpret_cast<const bf16x8*>(&sfr[16 + lrow][quad * 8 + ks * 32]);
            acc[0][0] = __builtin_amdgcn_mfma_f32_16x16x32_bf16(af0, breg[0][ks], acc[0][0], 0, 0, 0);
            acc[0][1] = __builtin_amdgcn_mfma_f32_16x16x32_bf16(af0, breg[1][ks], acc[0][1], 0, 0, 0);
            acc[1][0] = __builtin_amdgcn_mfma_f32_16x16x32_bf16(af1, breg[0][ks], acc[1][0], 0, 0, 0);
            acc[1][1] = __builtin_amdgcn_mfma_f32_16x16x32_bf16(af1, breg[1][ks], acc[1][1], 0, 0, 0);
        }
        #pragma unroll
        for (int mt = 0; mt < 2; ++mt) {
            #pragma unroll
            for (int nt = 0; nt < 2; ++nt) {
                const int n = w * 32 + nt * 16 + lrow;
                #pragma unroll
                for (int r = 0; r < 4; ++r) {
                    const int m = mt * 16 + quad * 4 + r;
                    const int row = base + m;
                    if (row < NPD) {
                        const float v = acc[mt][nt][r];
                        out[(size_t)(SEG * NPD + row) * OUTC + n] = v;
                        lsum[nt] += v; lsq[nt] += v * v;
                    }
                }
            }
        }
    };

    auto valid = [&](int t) { return (rbase + t * BROWS) < NPD; };  // block-uniform

    // ---- prologue: fill pipeline ----
    issue_idx(0, iaA, ibA);
    if (valid(1)) issue_idx(1, iaB, ibB);
    issue_feat(0, iaA, ibA);           // only exposed idx-latency stall per block

    // ---- even/odd unrolled pipeline: all reg-set choices compile-time ----
    for (int p = 0; p < NB / 2; ++p) {
        const int t0 = p * 2, t1 = t0 + 1;
        // ---- even batch: feat uses B, idx refills A ----
        const bool u0 = valid(t0);
        const bool u1 = valid(t1);
        if (u0) pack_lds(s_feat[0]);
        if (u1) issue_feat(t1, iaB, ibB);
        if (t0 + 2 < NB && valid(t0 + 2)) issue_idx(t0 + 2, iaA, ibA);
        asm volatile("s_waitcnt lgkmcnt(0)" ::: "memory");  // my ds_writes visible
        __builtin_amdgcn_s_barrier();                        // NO vmcnt drain
        if (u0) compute_store(t0, s_feat[0]);
        // ---- odd batch: feat uses A, idx refills B ----
        if (u1) pack_lds(s_feat[1]);
        if (t0 + 2 < NB && valid(t0 + 2)) issue_feat(t0 + 2, iaA, ibA);
        if (t1 + 2 < NB && valid(t1 + 2)) issue_idx(t1 + 2, iaB, ibB);
        asm volatile("s_waitcnt lgkmcnt(0)" ::: "memory");
        __builtin_amdgcn_s_barrier();
        if (u1) compute_store(t1, s_feat[1]);
    }

    atomicAdd(&s_sum[w * 32 + lrow], lsum[0]);
    atomicAdd(&s_sq [w * 32 + lrow], lsq[0]);
    atomicAdd(&s_sum[w * 32 + 16 + lrow], lsum[1]);
    atomicAdd(&s_sq [w * 32 + 16 + lrow], lsq[1]);
    __syncthreads();
    if (tid < OUTC) {
        atomicAdd(&stats[tid], s_sum[tid]);
        atomicAdd(&stats[OUTC + tid], s_sq[tid]);
    }
}

__global__ __launch_bounds__(256, 2) void compute_x_kernel(
    const float* __restrict__ atom_repr, const float* __restrict__ bond_repr,
    const int* __restrict__ a1, const int* __restrict__ b1,
    const int* __restrict__ a2, const int* __restrict__ b2,
    const int* __restrict__ a3, const int* __restrict__ b3,
    const int* __restrict__ a4, const int* __restrict__ b4,
    const unsigned short* __restrict__ Wcat, const float* __restrict__ bias,
    float* __restrict__ out, float* __restrict__ stats)
{
    __shared__ unsigned short s_feat[2][BROWS][LDST];   // ~42 KB -> 3 blocks/CU
    __shared__ float s_sum[OUTC], s_sq[OUTC];

    const int tid = threadIdx.x;
    if (tid < OUTC) { s_sum[tid] = 0.f; s_sq[tid] = 0.f; }
    // (loop barriers order this init before the final atomic accumulation)

    // LPT dispatch: blocks 0..976 -> deg4, ..., 2931..3907 -> deg1.
    // Longest blocks start first; the drain tail is deg-1 (shortest) blocks.
    const int bid   = blockIdx.x;
    const int s     = bid / NBLK;
    const int chunk = bid - s * NBLK;
    const int seg   = 3 - s;
    const float4* ar = (const float4*)atom_repr;
    const float4* br = (const float4*)bond_repr;

    if (seg == 3)
        run_seg<4>(ar, br, a4, b4, Wcat, bias, out, stats, s_feat, s_sum, s_sq, chunk, tid);
    else if (seg == 2)
        run_seg<3>(ar, br, a3, b3, Wcat, bias, out, stats, s_feat, s_sum, s_sq, chunk, tid);
    else if (seg == 1)
        run_seg<2>(ar, br, a2, b2, Wcat, bias, out, stats, s_feat, s_sum, s_sq, chunk, tid);
    else
        run_seg<1>(ar, br, a1, b1, Wcat, bias, out, stats, s_feat, s_sum, s_sq, chunk, tid);
}

__global__ void finalize_stats_kernel(float* stats) {
    const int o = threadIdx.x;  // 128
    const float inv_n = 1.0f / (float)N_ATOMS_C;
    const float mean = stats[o] * inv_n;
    const float var  = stats[OUTC + o] * inv_n - mean * mean;
    stats[o] = mean;
    stats[OUTC + o] = rsqrtf(var + BN_EPS);
}

#define BN_TOT (N_ATOMS_C * (OUTC / 4))   // 16,000,000 float4
#define BN_BLOCKS 2048

__global__ __launch_bounds__(256) void bn_relu_kernel(float* __restrict__ x,
                                                      const float* __restrict__ stats) {
    const int gid = blockIdx.x * 256 + threadIdx.x;
    // stride is a multiple of 32 -> channel quad (e & 31) is loop-invariant
    const int c4 = gid & 31;
    const float4 m = ((const float4*)stats)[c4];
    const float4 s = ((const float4*)stats)[32 + c4];
    const int stride = BN_BLOCKS * 256;
    for (size_t e = (size_t)gid; e < (size_t)BN_TOT; e += stride) {
        float4 v = ((float4*)x)[e];
        v.x = fmaxf((v.x - m.x) * s.x, 0.f);
        v.y = fmaxf((v.y - m.y) * s.y, 0.f);
        v.z = fmaxf((v.z - m.z) * s.z, 0.f);
        v.w = fmaxf((v.w - m.w) * s.w, 0.f);
        ((float4*)x)[e] = v;
    }
}

extern "C" void kernel_launch(void* const* d_in, const int* in_sizes, int n_in,
                              void* d_out, int out_size, void* d_ws, size_t ws_size,
                              hipStream_t stream) {
    const float* atom_repr = (const float*)d_in[0];
    const float* bond_repr = (const float*)d_in[1];
    const int*   a1 = (const int*)d_in[2];
    const int*   b1 = (const int*)d_in[3];
    const float* w1 = (const float*)d_in[4];
    const int*   a2 = (const int*)d_in[5];
    const int*   b2 = (const int*)d_in[6];
    const float* w2 = (const float*)d_in[7];
    const int*   a3 = (const int*)d_in[8];
    const int*   b3 = (const int*)d_in[9];
    const float* w3 = (const float*)d_in[10];
    const int*   a4 = (const int*)d_in[11];
    const int*   b4 = (const int*)d_in[12];
    const float* w4 = (const float*)d_in[13];
    const float* W_self = (const float*)d_in[14];
    const float* bias   = (const float*)d_in[15];

    float* out   = (float*)d_out;
    float* stats = (float*)d_ws;                                    // 256 f32
    unsigned short* Wcat = (unsigned short*)((char*)d_ws + 1024);   // bf16[4][128][320]

    pack_weights_kernel<<<(4 * OUTC * KTOT + 255) / 256, 256, 0, stream>>>(
        w1, w2, w3, w4, W_self, stats, Wcat);

    compute_x_kernel<<<NBLK * 4, 256, 0, stream>>>(
        atom_repr, bond_repr, a1, b1, a2, b2, a3, b3, a4, b4,
        Wcat, bias, out, stats);

    finalize_stats_kernel<<<1, 128, 0, stream>>>(stats);

    bn_relu_kernel<<<BN_BLOCKS, 256, 0, stream>>>(out, stats);
}